// Round 2
// baseline (964.179 us; speedup 1.0000x reference)
//
#include <hip/hip_runtime.h>
#include <math.h>

#define N 8192
#define NF4 2048  // N/4 float4s per row

// Sinkhorn via potentials: u_i = LSE_j(s_ij - v_j); v'_j = LSE_i(s_ij - u_i).
// Fused strip pass: block owns R rows; computes u for its rows AND the strip's
// column partial sums pt[strip][j] = sum_i exp(s_ij - v_j - u_i) from ONE read
// of s (v'_j = v_j + log(sum over strips)). Row phases are software-pipelined
// to ONE barrier per row:
//   between barriers: P3(r-1) | P2(r) | P1(r+1) | load(r+2)
//   P1: a = s - v, wave max, post    P2: e = exp(a-bm), wave sum, post
//   P3: acc += e / tot
// LDS red[parity][max|sum][wave]: every slot's read and its next overwrite are
// separated by a barrier (verified per slot), so one barrier/row is race-free.

__device__ __forceinline__ float wave_max(float m) {
#pragma unroll
  for (int off = 32; off > 0; off >>= 1) m = fmaxf(m, __shfl_xor(m, off, 64));
  return m;
}
__device__ __forceinline__ float wave_sum(float s) {
#pragma unroll
  for (int off = 32; off > 0; off >>= 1) s += __shfl_xor(s, off, 64);
  return s;
}

template <int R>
__global__ __launch_bounds__(256, 2) void fused_pass(
    const float* __restrict__ s, const float* __restrict__ v,
    float* __restrict__ u, float* __restrict__ pt, int use_v) {
  static_assert(R % 4 == 0 && R >= 8, "pipeline needs R%4==0, R>=8");
  const int t = threadIdx.x;
  const int wid = t >> 6, lane = t & 63;
  const int row0 = blockIdx.x * R;
  __shared__ float4 vsh[8][256];
  __shared__ float red[2][2][4];  // [row parity][0=max,1=sum][wave]

  {  // each thread writes and later reads ONLY its own vsh slots -> no barrier
    const float4* v4 = (const float4*)v;
#pragma unroll
    for (int k = 0; k < 8; ++k)
      vsh[k][t] = use_v ? v4[t + k * 256] : make_float4(0.f, 0.f, 0.f, 0.f);
  }

  float acc[32];
#pragma unroll
  for (int i = 0; i < 32; ++i) acc[i] = 0.f;

  const float4* s4 = (const float4*)s + (size_t)row0 * NF4;
  float4 b0[8], b1[8], b2[8], b3[8];
  float bmP = 0.f;  // bm of the row currently awaiting P3

  auto LOAD = [&](float4(&b)[8], int r) {
    const float4* p = s4 + (size_t)r * NF4;
#pragma unroll
    for (int k = 0; k < 8; ++k) b[k] = p[t + k * 256];
  };
  auto P1 = [&](float4(&b)[8], int r) {
    float m0 = -INFINITY, m1 = -INFINITY, m2 = -INFINITY, m3 = -INFINITY;
#pragma unroll
    for (int k = 0; k < 8; ++k) {
      const float4 vv = vsh[k][t];
      b[k].x -= vv.x; b[k].y -= vv.y; b[k].z -= vv.z; b[k].w -= vv.w;
      m0 = fmaxf(m0, b[k].x); m1 = fmaxf(m1, b[k].y);
      m2 = fmaxf(m2, b[k].z); m3 = fmaxf(m3, b[k].w);
    }
    const float m = wave_max(fmaxf(fmaxf(m0, m1), fmaxf(m2, m3)));
    if (lane == 0) red[r & 1][0][wid] = m;
  };
  auto P2 = [&](float4(&b)[8], int r) -> float {
    const float* rm = red[r & 1][0];
    const float bm = fmaxf(fmaxf(rm[0], rm[1]), fmaxf(rm[2], rm[3]));
    float s0 = 0.f, s1 = 0.f, s2 = 0.f, s3 = 0.f;
#pragma unroll
    for (int k = 0; k < 8; ++k) {
      b[k].x = __expf(b[k].x - bm); b[k].y = __expf(b[k].y - bm);
      b[k].z = __expf(b[k].z - bm); b[k].w = __expf(b[k].w - bm);
      s0 += b[k].x; s1 += b[k].y; s2 += b[k].z; s3 += b[k].w;
    }
    const float ss = wave_sum((s0 + s1) + (s2 + s3));
    if (lane == 0) red[r & 1][1][wid] = ss;
    return bm;
  };
  auto P3 = [&](float4(&b)[8], int r, float bm) {
    const float* rs = red[r & 1][1];
    const float tot = (rs[0] + rs[1]) + (rs[2] + rs[3]);
    const float inv = 1.0f / tot;
#pragma unroll
    for (int k = 0; k < 8; ++k) {
      acc[4 * k + 0] = fmaf(b[k].x, inv, acc[4 * k + 0]);
      acc[4 * k + 1] = fmaf(b[k].y, inv, acc[4 * k + 1]);
      acc[4 * k + 2] = fmaf(b[k].z, inv, acc[4 * k + 2]);
      acc[4 * k + 3] = fmaf(b[k].w, inv, acc[4 * k + 3]);
    }
    if (t == 0) u[row0 + r] = bm + __logf(tot);
  };

  // ---- prologue ----
  LOAD(b0, 0);
  LOAD(b1, 1);
  P1(b0, 0);
  __syncthreads();
  // step 0
  LOAD(b2, 2);
  bmP = P2(b0, 0);
  P1(b1, 1);
  __syncthreads();
  // step 1
  LOAD(b3, 3);
  P3(b0, 0, bmP);
  bmP = P2(b1, 1);
  P1(b2, 2);
  __syncthreads();
  // ---- main: steps 2 .. R-3 (buffers rotate mod 4, statically indexed) ----
#pragma unroll 1
  for (int k = 2; k <= R - 6; k += 4) {
    LOAD(b0, k + 2);
    P3(b1, k - 1, bmP);
    bmP = P2(b2, k);
    P1(b3, k + 1);
    __syncthreads();

    LOAD(b1, k + 3);
    P3(b2, k, bmP);
    bmP = P2(b3, k + 1);
    P1(b0, k + 2);
    __syncthreads();

    LOAD(b2, k + 4);
    P3(b3, k + 1, bmP);
    bmP = P2(b0, k + 2);
    P1(b1, k + 3);
    __syncthreads();

    LOAD(b3, k + 5);
    P3(b0, k + 2, bmP);
    bmP = P2(b1, k + 3);
    P1(b2, k + 4);
    __syncthreads();
  }
  // ---- epilogue: steps R-2, R-1, final P3 ----
  P3(b1, R - 3, bmP);  // (R-3)&3 == 1 since R%4==0
  bmP = P2(b2, R - 2);
  P1(b3, R - 1);
  __syncthreads();
  P3(b2, R - 2, bmP);
  bmP = P2(b3, R - 1);
  __syncthreads();
  P3(b3, R - 1, bmP);

  float4* p4 = (float4*)(pt + (size_t)blockIdx.x * N);
#pragma unroll
  for (int k = 0; k < 8; ++k)
    p4[t + k * 256] =
        make_float4(acc[4 * k], acc[4 * k + 1], acc[4 * k + 2], acc[4 * k + 3]);
}

// Stage 1: group-sum strips. ps[g][j] = sum over per_group strips of pt.
__global__ __launch_bounds__(256) void combine1(const float* __restrict__ pt,
                                                float* __restrict__ ps,
                                                int per_group) {
  const int j = blockIdx.x * 256 + threadIdx.x;
  const int g = blockIdx.y;
  const float* p = pt + (size_t)g * per_group * N + j;
  float acc = 0.f;
  for (int c = 0; c < per_group; ++c) acc += p[(size_t)c * N];
  ps[(size_t)g * N + j] = acc;
}

// Stage 2: v'_j = (add_old ? v_j : 0) + log(sum_g ps[g][j])
__global__ __launch_bounds__(256) void combine2(const float* __restrict__ ps,
                                                float* __restrict__ v,
                                                int ngroups, int add_old) {
  const int j = blockIdx.x * 256 + threadIdx.x;
  float T = 0.f;
  for (int g = 0; g < ngroups; ++g) T += ps[(size_t)g * N + j];
  const float lv = __logf(T);
  v[j] = add_old ? v[j] + lv : lv;
}

// out = exp(s - u_i - v_j)
__global__ __launch_bounds__(256) void finalize_k(const float* __restrict__ s,
                                                  const float* __restrict__ u,
                                                  const float* __restrict__ v,
                                                  float* __restrict__ out) {
  const size_t idx = (size_t)blockIdx.x * 256 + threadIdx.x;  // float4 index
  const int row = (int)(idx >> 11);
  const int c4 = (int)(idx & 2047);
  const float4 sv = ((const float4*)s)[idx];
  const float4 vv = ((const float4*)v)[c4];
  const float ur = u[row];
  float4 o;
  o.x = __expf(sv.x - ur - vv.x);
  o.y = __expf(sv.y - ur - vv.y);
  o.z = __expf(sv.z - ur - vv.z);
  o.w = __expf(sv.w - ur - vv.w);
  ((float4*)out)[idx] = o;
}

extern "C" void kernel_launch(void* const* d_in, const int* in_sizes, int n_in,
                              void* d_out, int out_size, void* d_ws, size_t ws_size,
                              hipStream_t stream) {
  const float* s = (const float*)d_in[0];
  float* out = (float*)d_out;
  float* ws = (float*)d_ws;

  // workspace: u[N] | v[N] | ps[8*N] | pt[nstrips*N]
  const size_t avail = ws_size / sizeof(float);
  int nstrips = 512;
  while (nstrips > 128 && (size_t)(10 + nstrips) * N > avail) nstrips >>= 1;
  float* u = ws;
  float* v = ws + N;
  float* ps = ws + 2 * N;
  float* pt = ws + 10 * N;
  const int G = 8;
  const int per_group = nstrips / G;

  for (int p = 0; p < 5; ++p) {
    const int use_v = p > 0 ? 1 : 0;
    switch (nstrips) {
      case 512:
        fused_pass<16><<<512, 256, 0, stream>>>(s, v, u, pt, use_v);
        break;
      case 256:
        fused_pass<32><<<256, 256, 0, stream>>>(s, v, u, pt, use_v);
        break;
      default:
        fused_pass<64><<<128, 256, 0, stream>>>(s, v, u, pt, use_v);
        break;
    }
    combine1<<<dim3(N / 256, G), 256, 0, stream>>>(pt, ps, per_group);
    combine2<<<N / 256, 256, 0, stream>>>(ps, v, G, p > 0 ? 1 : 0);
  }
  finalize_k<<<(N / 256) * NF4, 256, 0, stream>>>(s, u, v, out);
}